// Round 8
// baseline (151.497 us; speedup 1.0000x reference)
//
#include <hip/hip_runtime.h>

#define B_ROWS 4096
#define T_LEN  2048
#define TB     16                 // timesteps per register block
#define NBLK   (T_LEN / TB)       // 128 (even)

// ---- DPP butterfly via builtins, combiner-friendly form ----
// old = src, bound_ctrl = false, full masks: exactly the pattern
// GCNDPPCombine fuses into a single v_add_f32_dpp (dst, dpp(x), x).
// Semantics identical to R2/R4-proven version for these ctrls (every lane
// has a valid in-row source, so 'old' is never read).
template<int CTRL>
__device__ __forceinline__ float dpp_add(float x) {
  int xi = __builtin_bit_cast(int, x);
  int y  = __builtin_amdgcn_update_dpp(xi, xi, CTRL, 0xf, 0xf, false);
  return x + __builtin_bit_cast(float, y);
}

// Butterfly over each 16-lane row: every lane ends with its row's sum.
__device__ __forceinline__ float allreduce16(float x) {
  x = dpp_add<0xB1>(x);    // quad_perm [1,0,3,2] : xor 1
  x = dpp_add<0x4E>(x);    // quad_perm [2,3,0,1] : xor 2
  x = dpp_add<0x141>(x);   // row_half_mirror     : xor 4
  x = dpp_add<0x140>(x);   // row_mirror          : xor 8
  return x;
}

// One register block: 16 timesteps of (eps,hs) = 8 float4 = 32 VGPRs.
struct Blk { float4 q[8]; };

__device__ __forceinline__ void load_blk(const float4* __restrict__ src,
                                         Blk& b) {
#pragma unroll
  for (int i = 0; i < 8; ++i) b.q[i] = src[i];   // broadcast within 16 lanes
}

struct Pre { float dpre[TB - 1]; float hw[TB]; float pre15; };

__device__ __forceinline__ void extract(const Blk& b, float w0n, float bnn,
                                        float w1n, Pre& p) {
  float pre[TB];
#pragma unroll
  for (int i = 0; i < 8; ++i) {
    pre[2 * i]       = fmaf(b.q[i].x, w0n, bnn);
    p.hw[2 * i]      = b.q[i].y * w1n;
    pre[2 * i + 1]   = fmaf(b.q[i].z, w0n, bnn);
    p.hw[2 * i + 1]  = b.q[i].w * w1n;
  }
#pragma unroll
  for (int t = 0; t < TB - 1; ++t) p.dpre[t] = pre[t + 1] - pre[t];
  p.pre15 = pre[TB - 1];
}

// 16 steps in z-form (z = -log2e * z1).  CHAIN per step:
//   s1 -> fma(z') -> exp2 -> fma(d) -> rcp -> 4 fused dpp-adds -> s1'
// The s0/output path is software-pipelined ONE STEP BEHIND: step t-1's
// s0-butterfly + latch issue right after step t's exp2 (its stall window).
__device__ __forceinline__ void compute16(const Pre& p, float nextq0x,
                                          bool peek, float& z, float invc1,
                                          float ratio, float w0n, float bnn,
                                          int j, float& keep, float& v0p,
                                          float* __restrict__ outp) {
#pragma unroll
  for (int t = 0; t < TB; ++t) {
    float e = __builtin_amdgcn_exp2f(z);          // chain head: issue first
    // previous step's output path fills the exp2/rcp stall:
    {
      float s0 = allreduce16(v0p);
      keep = (j == t - 1) ? s0 : keep;            // t=0: j==-1 never true
    }
    float d  = fmaf(e, invc1, invc1);             // (1+e)/c1
    float r  = __builtin_amdgcn_rcpf(d);          // c1 * sigmoid(z1)
    float s1 = allreduce16(r);                    // chain: gamma-path sum
    float dpre_t = (t < TB - 1)
                     ? p.dpre[t]
                     : (peek ? (fmaf(nextq0x, w0n, bnn) - p.pre15) : 0.0f);
    float P = z + dpre_t;                         // off-chain side branch
    v0p = r * ratio;                              // c0*sigmoid, consumed t+1
    z   = fmaf(-p.hw[t], s1, P);                  // z' correct in ALL lanes
  }
  // tail: step TB-1's output (latch t-1 of NEXT call handles nothing here)
  float s0 = allreduce16(v0p);
  keep = (j == TB - 1) ? s0 : keep;
  outp[j] = keep;     // 16 consecutive floats per row per block
  keep = 0.0f;
  v0p  = 0.0f;        // next call's t=0 butterfly sums zeros (latch dead)
}

__global__ __launch_bounds__(64) void gsm_scan_kernel(
    const float* __restrict__ inp, const float* __restrict__ W1f,
    const float* __restrict__ b1f, const float* __restrict__ W2f,
    float* __restrict__ out) {
  const int lane = threadIdx.x;       // 0..63
  const int grp  = lane >> 4;         // row within wave, 0..3
  const int j    = lane & 15;         // hidden unit
  const int row  = (blockIdx.x << 2) + grp;

  const float LOG2E = 1.4426950408889634f;
  const float w0n = -LOG2E * W1f[j];
  const float w1n = -LOG2E * W1f[16 + j];
  const float bnn = -LOG2E * b1f[j];
  const float w2j = W2f[j];
  const float c0  = w2j * W1f[j];              // output-path coefficient
  const float c1  = w2j * W1f[16 + j] * 0.1f;  // gamma-path coeff (inv_eta)
  const float invc1 = 1.0f / c1;
  const float ratio = c0 * invc1;              // v0 = ratio * (c1*sig)

  const float4* src = (const float4*)(inp + (size_t)row * (2 * T_LEN));
  float* outrow = out + (size_t)row * T_LEN;

  Blk A, Bb;
  Pre p;
  load_blk(src, A);                  // block 0
  load_blk(src + 8, Bb);             // block 1
  float z    = fmaf(A.q[0].x, w0n, bnn);  // z0 = pre0 (gamma0 = 0)
  float keep = 0.0f, v0p = 0.0f;

#pragma unroll 1
  for (int b = 0; b < NBLK; b += 2) {
    // ---- phase 1: block b from A; prefetch b+2 into A's (now dead) regs
    extract(A, w0n, bnn, w1n, p);
    if (b + 2 < NBLK) load_blk(src + (size_t)(b + 2) * 8, A);
    compute16(p, Bb.q[0].x, true, z, invc1, ratio, w0n, bnn, j, keep, v0p,
              outrow + b * TB);
    // ---- phase 2: block b+1 from Bb; prefetch b+3 into Bb's regs
    extract(Bb, w0n, bnn, w1n, p);
    if (b + 3 < NBLK) load_blk(src + (size_t)(b + 3) * 8, Bb);
    compute16(p, A.q[0].x, (b + 2 < NBLK), z, invc1, ratio, w0n, bnn, j,
              keep, v0p, outrow + (b + 1) * TB);
  }
}

extern "C" void kernel_launch(void* const* d_in, const int* in_sizes, int n_in,
                              void* d_out, int out_size, void* d_ws,
                              size_t ws_size, hipStream_t stream) {
  const float* inp = (const float*)d_in[0];   // (B, T, 2) f32
  const float* W1  = (const float*)d_in[1];   // (2, 16)
  const float* b1  = (const float*)d_in[2];   // (16,)
  const float* W2  = (const float*)d_in[3];   // (16, 1)
  // d_in[4] = b2 : unused by the reference computation
  float* out = (float*)d_out;                 // (B, T) f32

  dim3 grid(B_ROWS / 4);   // 1024 waves; wall = 2048 steps x chain length,
  dim3 block(64);          // so chain op-count is the only lever
  hipLaunchKernelGGL(gsm_scan_kernel, grid, block, 0, stream,
                     inp, W1, b1, W2, out);
}

// Round 9
// 120.233 us; speedup vs baseline: 1.2600x; 1.2600x over previous
//
#include <hip/hip_runtime.h>

#define B_ROWS 4096
#define T_LEN  2048
#define TB     16                 // timesteps per register block
#define NBLK   (T_LEN / TB)       // 128 (even)

// ---- DPP butterfly: mov_dpp (UNDEF old) + add ----
// GCNDPPCombine fuses mov_dpp+add into one v_add_f32_dpp only when the
// mov's old operand is undef (or the op identity). update_dpp forces an
// explicit old (R7: 0 -> not fused, 140cy chain; R8: tied x -> extra movs,
// regression). mov_dpp is the undef-old form. bound_ctrl=1 + full masks:
// unconditionally combinable, and no ctrl here has invalid lanes.
template<int CTRL>
__device__ __forceinline__ float dpp_add(float x) {
  int y = __builtin_amdgcn_mov_dpp(__builtin_bit_cast(int, x),
                                   CTRL, 0xf, 0xf, true);
  return x + __builtin_bit_cast(float, y);
}

// Butterfly over each 16-lane row: every lane ends with its row's sum.
__device__ __forceinline__ float allreduce16(float x) {
  x = dpp_add<0xB1>(x);    // quad_perm [1,0,3,2] : xor 1
  x = dpp_add<0x4E>(x);    // quad_perm [2,3,0,1] : xor 2
  x = dpp_add<0x141>(x);   // row_half_mirror     : xor 4
  x = dpp_add<0x140>(x);   // row_mirror          : xor 8
  return x;
}

// One register block: 16 timesteps of (eps,hs) = 8 float4 = 32 VGPRs.
struct Blk { float4 q[8]; };

__device__ __forceinline__ void load_blk(const float4* __restrict__ src,
                                         Blk& b) {
#pragma unroll
  for (int i = 0; i < 8; ++i) b.q[i] = src[i];   // broadcast within 16 lanes
}

struct Pre { float dpre[TB - 1]; float hw[TB]; float pre15; };

__device__ __forceinline__ void extract(const Blk& b, float w0n, float bnn,
                                        float w1n, Pre& p) {
  float pre[TB];
#pragma unroll
  for (int i = 0; i < 8; ++i) {
    pre[2 * i]       = fmaf(b.q[i].x, w0n, bnn);
    p.hw[2 * i]      = b.q[i].y * w1n;
    pre[2 * i + 1]   = fmaf(b.q[i].z, w0n, bnn);
    p.hw[2 * i + 1]  = b.q[i].w * w1n;
  }
#pragma unroll
  for (int t = 0; t < TB - 1; ++t) p.dpre[t] = pre[t + 1] - pre[t];
  p.pre15 = pre[TB - 1];
}

// 16 steps in z-form: z = gamma*w1n + pre (everything pre-scaled by -log2e).
// CHAIN (per step): exp2 -> fma -> rcp -> butterfly -> fma.  All 16 lanes
// run the c1 path so every lane holds a correct s1 and correct z.
// OFF-CHAIN: P = z + dpre; v0 = ratio*r (c0 path); s0 butterfly; latch.
__device__ __forceinline__ void compute16(const Pre& p, float nextq0x,
                                          bool peek, float& z, float invc1,
                                          float ratio, float w0n, float bnn,
                                          int j, float* __restrict__ outp) {
  float keep = 0.0f;
#pragma unroll
  for (int t = 0; t < TB; ++t) {
    float e  = __builtin_amdgcn_exp2f(z);          // exp(-z1)
    float d  = fmaf(e, invc1, invc1);              // (1+e)/c1
    float r  = __builtin_amdgcn_rcpf(d);           // c1 * sigmoid(z1)
    float s1 = allreduce16(r);                     // chain: gamma-path sum
    // off-chain work (fills trans/butterfly stall slots):
    float dpre_t = (t < TB - 1)
                     ? p.dpre[t]
                     : (peek ? (fmaf(nextq0x, w0n, bnn) - p.pre15) : 0.0f);
    float P  = z + dpre_t;
    float v0 = r * ratio;                          // c0 * sigmoid
    float s0 = allreduce16(v0);                    // output-path sum
    z    = fmaf(-p.hw[t], s1, P);                  // z' correct in ALL lanes
    keep = (j == t) ? s0 : keep;                   // branchless latch
  }
  outp[j] = keep;   // 16 consecutive floats per row per block
}

__global__ __launch_bounds__(64) void gsm_scan_kernel(
    const float* __restrict__ inp, const float* __restrict__ W1f,
    const float* __restrict__ b1f, const float* __restrict__ W2f,
    float* __restrict__ out) {
  const int lane = threadIdx.x;       // 0..63
  const int grp  = lane >> 4;         // row within wave, 0..3
  const int j    = lane & 15;         // hidden unit
  const int row  = (blockIdx.x << 2) + grp;

  const float LOG2E = 1.4426950408889634f;
  const float w0n = -LOG2E * W1f[j];
  const float w1n = -LOG2E * W1f[16 + j];
  const float bnn = -LOG2E * b1f[j];
  const float w2j = W2f[j];
  const float c0  = w2j * W1f[j];              // output-path coefficient
  const float c1  = w2j * W1f[16 + j] * 0.1f;  // gamma-path coeff (inv_eta)
  const float invc1 = 1.0f / c1;
  const float ratio = c0 * invc1;              // v0 = ratio * (c1*sig)

  const float4* src = (const float4*)(inp + (size_t)row * (2 * T_LEN));
  float* outrow = out + (size_t)row * T_LEN;

  Blk A, Bb;
  Pre p;
  load_blk(src, A);                  // block 0
  load_blk(src + 8, Bb);             // block 1
  float z = fmaf(A.q[0].x, w0n, bnn);  // z0 = pre0 (gamma0 = 0)

#pragma unroll 1
  for (int b = 0; b < NBLK; b += 2) {
    // ---- phase 1: block b from A; prefetch b+2 into A's (now dead) regs
    extract(A, w0n, bnn, w1n, p);
    if (b + 2 < NBLK) load_blk(src + (size_t)(b + 2) * 8, A);
    compute16(p, Bb.q[0].x, true, z, invc1, ratio, w0n, bnn, j,
              outrow + b * TB);
    // ---- phase 2: block b+1 from Bb; prefetch b+3 into Bb's regs
    extract(Bb, w0n, bnn, w1n, p);
    if (b + 3 < NBLK) load_blk(src + (size_t)(b + 3) * 8, Bb);
    compute16(p, A.q[0].x, (b + 2 < NBLK), z, invc1, ratio, w0n, bnn, j,
              outrow + (b + 1) * TB);
  }
}

extern "C" void kernel_launch(void* const* d_in, const int* in_sizes, int n_in,
                              void* d_out, int out_size, void* d_ws,
                              size_t ws_size, hipStream_t stream) {
  const float* inp = (const float*)d_in[0];   // (B, T, 2) f32
  const float* W1  = (const float*)d_in[1];   // (2, 16)
  const float* b1  = (const float*)d_in[2];   // (16,)
  const float* W2  = (const float*)d_in[3];   // (16, 1)
  // d_in[4] = b2 : unused by the reference computation
  float* out = (float*)d_out;                 // (B, T) f32

  dim3 grid(B_ROWS / 4);   // 1024 waves; wall = 2048 steps x chain length,
  dim3 block(64);          // so chain op-count is the only lever
  hipLaunchKernelGGL(gsm_scan_kernel, grid, block, 0, stream,
                     inp, W1, b1, W2, out);
}